// Round 7
// baseline (224.096 us; speedup 1.0000x reference)
//
#include <hip/hip_runtime.h>
#include <stdint.h>

#define N_BATCH 32
#define B_OBJ   36
#define D_DIM   2048
#define Q_DIM   1024

typedef __bf16 bf16x8  __attribute__((ext_vector_type(8)));
typedef float  f32x4   __attribute__((ext_vector_type(4)));
typedef float  f32x16  __attribute__((ext_vector_type(16)));

__device__ __forceinline__ uint16_t f2bf(float f) {
    uint32_t u = __builtin_bit_cast(uint32_t, f);
    uint32_t r = (u + 0x7FFFu + ((u >> 16) & 1u)) >> 16;   // RNE
    return (uint16_t)r;
}

__device__ __forceinline__ void gld_lds16(const void* g, void* l) {
    __builtin_amdgcn_global_load_lds(
        (const __attribute__((address_space(1))) uint32_t*)g,
        (__attribute__((address_space(3))) uint32_t*)l, 16, 0, 0);
}

// ---- transpose + fp32->bf16 for W1, W2 (2048x2048 each) ----
__global__ __launch_bounds__(256) void transpose_all(
    const float* __restrict__ W1, const float* __restrict__ W2,
    uint16_t* __restrict__ W1t, uint16_t* __restrict__ W2t) {
    __shared__ float tile[64][65];
    int gy = blockIdx.y;
    const float* W; uint16_t* Wt; int k0;
    if (gy < 32) { W = W1; Wt = W1t; k0 = gy * 64; }
    else         { W = W2; Wt = W2t; k0 = (gy - 32) * 64; }
    int n0 = blockIdx.x * 64;
    int t = threadIdx.x;
    {
        int r = t >> 4, c = (t & 15) * 4;
#pragma unroll
        for (int p = 0; p < 4; ++p)
            *(float4*)&tile[r + p * 16][c] =
                *(const float4*)&W[(size_t)(k0 + r + p * 16) * 2048 + n0 + c];
    }
    __syncthreads();
    {
        int n = t >> 2, kb = (t & 3) * 16;
#pragma unroll
        for (int g4 = 0; g4 < 4; ++g4) {
            int k = kb + g4 * 4;
            ushort4 o;
            o.x = f2bf(tile[k][n]);     o.y = f2bf(tile[k + 1][n]);
            o.z = f2bf(tile[k + 2][n]); o.w = f2bf(tile[k + 3][n]);
            *(ushort4*)&Wt[(size_t)(n0 + n) * 2048 + k0 + k] = o;
        }
    }
}

// ---- q-path fp32 split-K: qpart[kz][n][e] ----
__global__ __launch_bounds__(256) void qe_f32(
    const float* __restrict__ q, const float* __restrict__ W3,
    float* __restrict__ qpart) {
    __shared__ float qs[128][32];
    int t = threadIdx.x;
    int e0 = blockIdx.x * 64;
    int kbase = blockIdx.y * 128;
    {
        int nn = t >> 3, kg = (t & 7) * 16;
#pragma unroll
        for (int p = 0; p < 4; ++p) {
            float4 f = *(const float4*)&q[(size_t)nn * Q_DIM + kbase + kg + p * 4];
            qs[kg + p * 4 + 0][nn] = f.x; qs[kg + p * 4 + 1][nn] = f.y;
            qs[kg + p * 4 + 2][nn] = f.z; qs[kg + p * 4 + 3][nn] = f.w;
        }
    }
    __syncthreads();
    int n = t >> 3, e8 = (t & 7) * 8;
    float acc[8] = {};
#pragma unroll 4
    for (int k = 0; k < 128; ++k) {
        float qv = qs[k][n];
        float4 wa = *(const float4*)&W3[(size_t)(kbase + k) * D_DIM + e0 + e8];
        float4 wb = *(const float4*)&W3[(size_t)(kbase + k) * D_DIM + e0 + e8 + 4];
        acc[0] += qv * wa.x; acc[1] += qv * wa.y; acc[2] += qv * wa.z; acc[3] += qv * wa.w;
        acc[4] += qv * wb.x; acc[5] += qv * wb.y; acc[6] += qv * wb.z; acc[7] += qv * wb.w;
    }
    float* dst = qpart + (size_t)blockIdx.y * 32 * D_DIM + (size_t)n * D_DIM + e0 + e8;
    *(float4*)dst = *(float4*)&acc[0];
    *(float4*)(dst + 4) = *(float4*)&acc[4];
}

// ---- fused: qe = relu(sum_z qpart + b3); u[n,i,:] = bf16(v[n,i,:]*qe) ----
__global__ __launch_bounds__(256) void qe_makeu(
    const float* __restrict__ qpart, const float* __restrict__ b3,
    const float* __restrict__ v, uint16_t* __restrict__ u) {
    int n = blockIdx.y;
    int c4 = blockIdx.x * 256 + threadIdx.x;
    const float4* p = (const float4*)qpart;
    size_t base = (size_t)n * 512 + c4;
    float4 s = p[base];
#pragma unroll
    for (int z = 1; z < 8; ++z) {
        float4 sz = p[(size_t)z * 16384 + base];
        s.x += sz.x; s.y += sz.y; s.z += sz.z; s.w += sz.w;
    }
    float4 b = ((const float4*)b3)[c4];
    float4 qe;
    qe.x = fmaxf(s.x + b.x, 0.f); qe.y = fmaxf(s.y + b.y, 0.f);
    qe.z = fmaxf(s.z + b.z, 0.f); qe.w = fmaxf(s.w + b.w, 0.f);
    const float4* v4 = (const float4*)v + (size_t)n * B_OBJ * 512 + c4;
    ushort4* u4 = (ushort4*)u + (size_t)n * B_OBJ * 512 + c4;
#pragma unroll 4
    for (int i = 0; i < B_OBJ; ++i) {
        float4 vv = v4[(size_t)i * 512];
        ushort4 o;
        o.x = f2bf(vv.x * qe.x); o.y = f2bf(vv.y * qe.y);
        o.z = f2bf(vv.z * qe.z); o.w = f2bf(vv.w * qe.w);
        u4[(size_t)i * 512] = o;
    }
}

// ---- GEMM: tile 64x64, 4 waves (wave = 32x32 mfma_32x32x16), BK=64, dbuf ----
// Staging: lane -> (row = lane&15, k8 = lane>>4); region = [k8][row16] 1 KiB.
// Region stride 544 u16 (1088 B) -> fragment b128 reads hit all 32 banks.
// mode 0: C = f32 y (no bias).  mode 1: C = relu(acc + bias) f32.
__global__ __launch_bounds__(256) void gemm64(
    const uint16_t* __restrict__ A,    // 1152 x 2048 bf16
    const uint16_t* __restrict__ Bt,   // 2048 x 2048 bf16 (n-major)
    const float* __restrict__ bias,
    float* __restrict__ C,
    int mode) {
    __shared__ __align__(16) uint16_t sm[17408];   // A: [0,8704) x2buf, B: [8704,17408)

    int t = threadIdx.x, lane = t & 63, wave = t >> 6;
    int l31 = lane & 31, khalf = lane >> 5;
    int mq = wave >> 1, nq = wave & 1;

    // XCD-aware swizzle: n-group = flat&7 pinned per XCD (B strip 1 MiB -> L2)
    int flat = blockIdx.y * 32 + blockIdx.x;
    int n_t = (flat & 7) * 4 + ((flat >> 3) & 3);
    int m_t = flat >> 5;
    int m0 = m_t * 64, n0 = n_t * 64;

    const uint16_t* Ab = A  + (size_t)m0 * D_DIM;
    const uint16_t* Bb = Bt + (size_t)n0 * D_DIM;

    // 16 regions/iter: r<8 = A[h=r>>2][g=r&3], else B. wave w stages r = w*4..w*4+3.
    const uint16_t* gp[4]; uint16_t* lp[4];
    {
        int ri = lane & 15, k8 = lane >> 4;
#pragma unroll
        for (int c = 0; c < 4; ++c) {
            int r = wave * 4 + c;
            if (r < 8) {
                int h = r >> 2, g = r & 3;
                gp[c] = Ab + (size_t)(g * 16 + ri) * D_DIM + h * 32 + k8 * 8;
                lp[c] = sm + h * 2176 + g * 544;
            } else {
                int rb = r - 8, h = rb >> 2, g = rb & 3;
                gp[c] = Bb + (size_t)(g * 16 + ri) * D_DIM + h * 32 + k8 * 8;
                lp[c] = sm + 8704 + h * 2176 + g * 544;
            }
        }
    }

    f32x16 acc = {};

    // prologue: fill buffer 0
#pragma unroll
    for (int c = 0; c < 4; ++c) gld_lds16(gp[c], lp[c]);

    for (int it = 0; it < 32; ++it) {
        int buf = it & 1;
        __syncthreads();                 // drains buf's loads
        if (it < 31) {
            int nxt = buf ^ 1;
#pragma unroll
            for (int c = 0; c < 4; ++c)
                gld_lds16(gp[c] + (size_t)(it + 1) * 64, lp[c] + nxt * 4352);
        }
        // fragment reads: row = q*32 + l31 -> g = q*2 + (l31>>4), ri = l31&15
        int gA = mq * 2 + (l31 >> 4), gB = nq * 2 + (l31 >> 4);
        int ri8 = (l31 & 15) * 8;
#pragma unroll
        for (int s = 0; s < 4; ++s) {
            int h = s >> 1, k8i = (s & 1) * 2 + khalf;
            bf16x8 af = *(const bf16x8*)(sm + buf * 4352 + h * 2176 +
                                         gA * 544 + k8i * 128 + ri8);
            bf16x8 bfr = *(const bf16x8*)(sm + 8704 + buf * 4352 + h * 2176 +
                                          gB * 544 + k8i * 128 + ri8);
            acc = __builtin_amdgcn_mfma_f32_32x32x16_bf16(af, bfr, acc, 0, 0, 0);
        }
    }

    // C/D layout (m74/m101): col = lane&31, row = (reg&3)+8*(reg>>2)+4*(lane>>5)
    int col = n0 + nq * 32 + l31;
    float b = (mode == 1) ? bias[col] : 0.f;
#pragma unroll
    for (int reg = 0; reg < 16; ++reg) {
        int row = m0 + mq * 32 + (reg & 3) + 8 * (reg >> 2) + 4 * khalf;
        float val = acc[reg] + b;
        if (mode == 1) val = fmaxf(val, 0.f);
        C[(size_t)row * D_DIM + col] = val;
    }
}

// ---- pairsum: x = bf16( sum_j relu(y_i + y_j + b1) ) ----
__global__ __launch_bounds__(256) void pairsum(
    const float* __restrict__ y, const float* __restrict__ b1,
    uint16_t* __restrict__ X) {
    int n = blockIdx.y;
    int d = blockIdx.x * 256 + threadIdx.x;
    const float* yb = y + (size_t)(n * B_OBJ) * D_DIM + d;
    float z[B_OBJ];
#pragma unroll
    for (int j = 0; j < B_OBJ; ++j) z[j] = yb[(size_t)j * D_DIM];
    float b = b1[d];
    uint16_t* xb = X + (size_t)(n * B_OBJ) * D_DIM + d;
#pragma unroll
    for (int i = 0; i < B_OBJ; ++i) {
        float zi = z[i] + b;
        float s = 0.f;
#pragma unroll
        for (int j = 0; j < B_OBJ; ++j) s += fmaxf(zi + z[j], 0.f);
        xb[(size_t)i * D_DIM] = f2bf(s);
    }
}

extern "C" void kernel_launch(void* const* d_in, const int* in_sizes, int n_in,
                              void* d_out, int out_size, void* d_ws, size_t ws_size,
                              hipStream_t stream) {
    const float* v  = (const float*)d_in[0];
    const float* q  = (const float*)d_in[1];
    const float* W1 = (const float*)d_in[2];
    const float* b1 = (const float*)d_in[3];
    const float* W2 = (const float*)d_in[4];
    const float* b2 = (const float*)d_in[5];
    const float* W3 = (const float*)d_in[6];
    const float* b3 = (const float*)d_in[7];
    float* out = (float*)d_out;

    char* ws = (char*)d_ws;
    uint16_t* W1t   = (uint16_t*)(ws + 0);           //  8 MiB
    uint16_t* W2t   = (uint16_t*)(ws + 8388608);     //  8 MiB
    uint16_t* u     = (uint16_t*)(ws + 16777216);    //  4.5 MiB
    float*    qpart = (float*)   (ws + 21495808);    //  2 MiB
    uint16_t* x     = (uint16_t*)(ws + 23592960);    //  4.5 MiB
    float*    y     = (float*)   (ws + 28311552);    //  9 MiB

    transpose_all<<<dim3(32, 64), 256, 0, stream>>>(W1, W2, W1t, W2t);

    qe_f32<<<dim3(32, 8), 256, 0, stream>>>(q, W3, qpart);
    qe_makeu<<<dim3(2, N_BATCH), 256, 0, stream>>>(qpart, b3, v, u);

    // y = u @ W1^T-form   (1152 x 2048)
    gemm64<<<dim3(32, 18), 256, 0, stream>>>(u, W1t, nullptr, y, 0);

    // x = pairsum(y) bf16
    pairsum<<<dim3(8, N_BATCH), 256, 0, stream>>>(y, b1, x);

    // out = relu(x @ W2^T-form + b2)
    gemm64<<<dim3(32, 18), 256, 0, stream>>>(x, W2t, b2, out, 1);
}

// Round 8
// 194.045 us; speedup vs baseline: 1.1549x; 1.1549x over previous
//
#include <hip/hip_runtime.h>
#include <stdint.h>

#define N_BATCH 32
#define B_OBJ   36
#define D_DIM   2048
#define Q_DIM   1024

typedef __bf16 bf16x8  __attribute__((ext_vector_type(8)));
typedef float  f32x16  __attribute__((ext_vector_type(16)));

__device__ __forceinline__ uint16_t f2bf(float f) {
    uint32_t u = __builtin_bit_cast(uint32_t, f);
    uint32_t r = (u + 0x7FFFu + ((u >> 16) & 1u)) >> 16;   // RNE
    return (uint16_t)r;
}

// Packed fragment layout for a 32-row (or 32-col) tile, K=2048:
//   flat = (tile32 * 128 + (k>>4)) * 512 + ((k>>3)&1) * 256 + (r&31) * 8 + (k&7)
// so a wave's (tile,k16) fragment load is base + lane*8 u16 = 16 B/lane, 1 KiB coalesced.
__device__ __forceinline__ size_t pk_idx(int row, int k) {
    return ((size_t)(row >> 5) * 128 + (k >> 4)) * 512 +
           ((k >> 3) & 1) * 256 + (row & 31) * 8 + (k & 7);
}

// ---- transpose + fp32->bf16 -> packed-fragment W (2048x2048 each) ----
__global__ __launch_bounds__(256) void transpose_all(
    const float* __restrict__ W1, const float* __restrict__ W2,
    uint16_t* __restrict__ PW1, uint16_t* __restrict__ PW2) {
    __shared__ float tile[64][65];
    int gy = blockIdx.y;
    const float* W; uint16_t* Wt; int k0;
    if (gy < 32) { W = W1; Wt = PW1; k0 = gy * 64; }
    else         { W = W2; Wt = PW2; k0 = (gy - 32) * 64; }
    int n0 = blockIdx.x * 64;
    int t = threadIdx.x;
    {
        int r = t >> 4, c = (t & 15) * 4;
#pragma unroll
        for (int p = 0; p < 4; ++p)
            *(float4*)&tile[r + p * 16][c] =
                *(const float4*)&W[(size_t)(k0 + r + p * 16) * 2048 + n0 + c];
    }
    __syncthreads();
    {
        int n = t >> 2, kb = (t & 3) * 16;
        int e = n0 + n;
#pragma unroll
        for (int g4 = 0; g4 < 4; ++g4) {
            int k = kb + g4 * 4;
            ushort4 o;
            o.x = f2bf(tile[k][n]);     o.y = f2bf(tile[k + 1][n]);
            o.z = f2bf(tile[k + 2][n]); o.w = f2bf(tile[k + 3][n]);
            *(ushort4*)&Wt[pk_idx(e, k0 + k)] = o;   // (k0+k)&7 in {0,4} -> 8B aligned
        }
    }
}

// ---- q-path fp32 split-K: qpart[kz][n][e] ----
__global__ __launch_bounds__(256) void qe_f32(
    const float* __restrict__ q, const float* __restrict__ W3,
    float* __restrict__ qpart) {
    __shared__ float qs[128][32];
    int t = threadIdx.x;
    int e0 = blockIdx.x * 64;
    int kbase = blockIdx.y * 128;
    {
        int nn = t >> 3, kg = (t & 7) * 16;
#pragma unroll
        for (int p = 0; p < 4; ++p) {
            float4 f = *(const float4*)&q[(size_t)nn * Q_DIM + kbase + kg + p * 4];
            qs[kg + p * 4 + 0][nn] = f.x; qs[kg + p * 4 + 1][nn] = f.y;
            qs[kg + p * 4 + 2][nn] = f.z; qs[kg + p * 4 + 3][nn] = f.w;
        }
    }
    __syncthreads();
    int n = t >> 3, e8 = (t & 7) * 8;
    float acc[8] = {};
#pragma unroll 4
    for (int k = 0; k < 128; ++k) {
        float qv = qs[k][n];
        float4 wa = *(const float4*)&W3[(size_t)(kbase + k) * D_DIM + e0 + e8];
        float4 wb = *(const float4*)&W3[(size_t)(kbase + k) * D_DIM + e0 + e8 + 4];
        acc[0] += qv * wa.x; acc[1] += qv * wa.y; acc[2] += qv * wa.z; acc[3] += qv * wa.w;
        acc[4] += qv * wb.x; acc[5] += qv * wb.y; acc[6] += qv * wb.z; acc[7] += qv * wb.w;
    }
    float* dst = qpart + (size_t)blockIdx.y * 32 * D_DIM + (size_t)n * D_DIM + e0 + e8;
    *(float4*)dst = *(float4*)&acc[0];
    *(float4*)(dst + 4) = *(float4*)&acc[4];
}

// ---- fused: qe = relu(sum_z qpart + b3); u packed = bf16(v * qe) ----
__global__ __launch_bounds__(256) void qe_makeu(
    const float* __restrict__ qpart, const float* __restrict__ b3,
    const float* __restrict__ v, uint16_t* __restrict__ u) {
    int n = blockIdx.y;
    int c4 = blockIdx.x * 256 + threadIdx.x;     // [0,512) float4-col
    int d = c4 * 4;
    const float4* p = (const float4*)qpart;
    size_t base = (size_t)n * 512 + c4;
    float4 s = p[base];
#pragma unroll
    for (int z = 1; z < 8; ++z) {
        float4 sz = p[(size_t)z * 16384 + base];
        s.x += sz.x; s.y += sz.y; s.z += sz.z; s.w += sz.w;
    }
    float4 b = ((const float4*)b3)[c4];
    float4 qe;
    qe.x = fmaxf(s.x + b.x, 0.f); qe.y = fmaxf(s.y + b.y, 0.f);
    qe.z = fmaxf(s.z + b.z, 0.f); qe.w = fmaxf(s.w + b.w, 0.f);
    const float4* v4 = (const float4*)v + (size_t)n * B_OBJ * 512 + c4;
#pragma unroll 4
    for (int i = 0; i < B_OBJ; ++i) {
        float4 vv = v4[(size_t)i * 512];
        ushort4 o;
        o.x = f2bf(vv.x * qe.x); o.y = f2bf(vv.y * qe.y);
        o.z = f2bf(vv.z * qe.z); o.w = f2bf(vv.w * qe.w);
        int row = n * B_OBJ + i;
        *(ushort4*)&u[pk_idx(row, d)] = o;       // d&7 in {0,4} -> aligned
    }
}

// ---- GEMM on packed fragments: no LDS, no barriers ----
// tile 64x64, 4 waves (2x2), wave = one 32x32 mfma_32x32x16 chain, K=2048.
// Register double-buffer of 4 k16-steps; 8 coalesced loads in flight.
// mode 0: C = acc (f32, row-major). mode 1: C = relu(acc + bias).
__global__ __launch_bounds__(256) void gemm_pk(
    const uint16_t* __restrict__ PA,   // 36 tiles x 128 k16 x 512
    const uint16_t* __restrict__ PB,   // 64 tiles x 128 k16 x 512
    const float* __restrict__ bias,
    float* __restrict__ C,
    int mode) {
    int t = threadIdx.x, lane = t & 63, wave = t >> 6;
    int l31 = lane & 31, khalf = lane >> 5;
    int mq = wave >> 1, nq = wave & 1;

    // XCD swizzle: flat&7 ~ XCD id -> each XCD works a 4-block n-group (1 MiB of PB, L2-resident)
    int flat = blockIdx.x + blockIdx.y * 32;
    int bn = (flat & 7) * 4 + ((flat >> 3) & 3);   // [0,32)
    int bm = flat >> 5;                            // [0,18)

    const uint16_t* pa = PA + (size_t)(bm * 2 + mq) * 65536 + lane * 8;
    const uint16_t* pb = PB + (size_t)(bn * 2 + nq) * 65536 + lane * 8;

    f32x16 acc = {};
    bf16x8 a0[4], b0[4], a1[4], b1[4];
#pragma unroll
    for (int u = 0; u < 4; ++u) {
        a0[u] = *(const bf16x8*)(pa + u * 512);
        b0[u] = *(const bf16x8*)(pb + u * 512);
    }
    for (int c = 0; c < 32; c += 2) {
#pragma unroll
        for (int u = 0; u < 4; ++u) {
            a1[u] = *(const bf16x8*)(pa + (size_t)(c + 1) * 2048 + u * 512);
            b1[u] = *(const bf16x8*)(pb + (size_t)(c + 1) * 2048 + u * 512);
        }
#pragma unroll
        for (int u = 0; u < 4; ++u)
            acc = __builtin_amdgcn_mfma_f32_32x32x16_bf16(a0[u], b0[u], acc, 0, 0, 0);
        if (c + 2 < 32) {
#pragma unroll
            for (int u = 0; u < 4; ++u) {
                a0[u] = *(const bf16x8*)(pa + (size_t)(c + 2) * 2048 + u * 512);
                b0[u] = *(const bf16x8*)(pb + (size_t)(c + 2) * 2048 + u * 512);
            }
        }
#pragma unroll
        for (int u = 0; u < 4; ++u)
            acc = __builtin_amdgcn_mfma_f32_32x32x16_bf16(a1[u], b1[u], acc, 0, 0, 0);
    }

    // C/D layout (m74/m101): col = lane&31, row = (reg&3)+8*(reg>>2)+4*(lane>>5)
    int col = bn * 64 + nq * 32 + l31;
    float b = (mode == 1) ? bias[col] : 0.f;
#pragma unroll
    for (int reg = 0; reg < 16; ++reg) {
        int row = bm * 64 + mq * 32 + (reg & 3) + 8 * (reg >> 2) + 4 * khalf;
        float val = acc[reg] + b;
        if (mode == 1) val = fmaxf(val, 0.f);
        C[(size_t)row * D_DIM + col] = val;
    }
}

// ---- pairsum: x_packed = bf16( sum_j relu(y_i + y_j + b1) ) ----
__global__ __launch_bounds__(256) void pairsum(
    const float* __restrict__ y, const float* __restrict__ b1,
    uint16_t* __restrict__ X) {
    int n = blockIdx.y;
    int d = blockIdx.x * 256 + threadIdx.x;
    const float* yb = y + (size_t)(n * B_OBJ) * D_DIM + d;
    float z[B_OBJ];
#pragma unroll
    for (int j = 0; j < B_OBJ; ++j) z[j] = yb[(size_t)j * D_DIM];
    float b = b1[d];
#pragma unroll
    for (int i = 0; i < B_OBJ; ++i) {
        float zi = z[i] + b;
        float s = 0.f;
#pragma unroll
        for (int j = 0; j < B_OBJ; ++j) s += fmaxf(zi + z[j], 0.f);
        X[pk_idx(n * B_OBJ + i, d)] = f2bf(s);
    }
}

extern "C" void kernel_launch(void* const* d_in, const int* in_sizes, int n_in,
                              void* d_out, int out_size, void* d_ws, size_t ws_size,
                              hipStream_t stream) {
    const float* v  = (const float*)d_in[0];
    const float* q  = (const float*)d_in[1];
    const float* W1 = (const float*)d_in[2];
    const float* b1 = (const float*)d_in[3];
    const float* W2 = (const float*)d_in[4];
    const float* b2 = (const float*)d_in[5];
    const float* W3 = (const float*)d_in[6];
    const float* b3 = (const float*)d_in[7];
    float* out = (float*)d_out;

    char* ws = (char*)d_ws;
    uint16_t* PW1   = (uint16_t*)(ws + 0);           //  8 MiB packed
    uint16_t* PW2   = (uint16_t*)(ws + 8388608);     //  8 MiB packed
    uint16_t* Pu    = (uint16_t*)(ws + 16777216);    //  4.5 MiB packed
    float*    qpart = (float*)   (ws + 21495808);    //  2 MiB
    uint16_t* Px    = (uint16_t*)(ws + 23592960);    //  4.5 MiB packed
    float*    y     = (float*)   (ws + 28311552);    //  9 MiB f32

    transpose_all<<<dim3(32, 64), 256, 0, stream>>>(W1, W2, PW1, PW2);

    qe_f32<<<dim3(32, 8), 256, 0, stream>>>(q, W3, qpart);
    qe_makeu<<<dim3(2, N_BATCH), 256, 0, stream>>>(qpart, b3, v, Pu);

    // y = u @ W1  (1152 x 2048 f32)
    gemm_pk<<<dim3(32, 18), 256, 0, stream>>>(Pu, PW1, nullptr, y, 0);

    // x = pairsum(y) -> packed bf16
    pairsum<<<dim3(8, N_BATCH), 256, 0, stream>>>(y, b1, Px);

    // out = relu(x @ W2 + b2)
    gemm_pk<<<dim3(32, 18), 256, 0, stream>>>(Px, PW2, b2, out, 1);
}